// Round 1
// baseline (167.883 us; speedup 1.0000x reference)
//
#include <hip/hip_runtime.h>
#include <stdint.h>

// DenseTNT postprocess: per batch row, greedy goal-NMS (2 m threshold, strict <)
// over score-descending order, select 6 modes, gather trajs + scores.
//
// Key insight: argsort+scan greedy NMS == 6 rounds of masked argmax
// ("best surviving candidate"), so no sort is needed. Tie-break must match
// stable argsort: equal score -> lower original index wins.

namespace {
constexpr int kB        = 128;
constexpr int kN        = 4096;
constexpr int kSteps    = 30;
constexpr int kModes    = 6;
constexpr int kTPB      = 256;
constexpr int kPerThread = kN / kTPB;  // 16 candidates per thread
constexpr float kThresh2 = 4.0f;       // THRESHOLD^2
}

// Monotone map float -> uint32 (preserves total order for all finite floats).
__device__ __forceinline__ unsigned int order_key(float f) {
    unsigned int u = __float_as_uint(f);
    return (u & 0x80000000u) ? ~u : (u | 0x80000000u);
}

__device__ __forceinline__ unsigned long long shfl_down_u64(unsigned long long v, int off) {
    unsigned int lo = (unsigned int)(v & 0xFFFFFFFFull);
    unsigned int hi = (unsigned int)(v >> 32);
    lo = __shfl_down(lo, off, 64);
    hi = __shfl_down(hi, off, 64);
    return (((unsigned long long)hi) << 32) | (unsigned long long)lo;
}

__global__ __launch_bounds__(kTPB)
void densetnt_nms_kernel(const float* __restrict__ scores,   // [B, N]
                         const float* __restrict__ trajs,    // [B, 2*P, N]
                         const float* __restrict__ goals,    // [B, 2, N]
                         float* __restrict__ out) {          // [B*6*60] trajs, then [B*6] scores
    const int b    = blockIdx.x;
    const int tid  = threadIdx.x;
    const int lane = tid & 63;

    __shared__ unsigned long long s_maxkey[kModes];
    __shared__ int   s_selidx[kModes];
    __shared__ float s_selscore[kModes];
    __shared__ int   s_count;

    const float* sc = scores + (size_t)b * kN;
    const float* gx = goals  + (size_t)b * 2 * kN;
    const float* gy = gx + kN;

    // Cache this thread's 16 candidates in registers (coalesced, stride-256).
    float my_sc[kPerThread], my_gx[kPerThread], my_gy[kPerThread];
    #pragma unroll
    for (int j = 0; j < kPerThread; ++j) {
        int i = tid + j * kTPB;
        my_sc[j] = sc[i];
        my_gx[j] = gx[i];
        my_gy[j] = gy[i];
    }

    if (tid < kModes) s_maxkey[tid] = 0ULL;   // 0 == "no valid candidate" sentinel
    if (tid == 0) s_count = 0;
    __syncthreads();

    unsigned int valid = 0xFFFFu;  // per-thread survival bitmask (16 candidates)

    for (int m = 0; m < kModes; ++m) {
        // Local masked argmax. Key: score (order-mapped) in high 32, inverted
        // index in low 32 -> max picks highest score, ties -> lowest index.
        unsigned long long best = 0ULL;
        #pragma unroll
        for (int j = 0; j < kPerThread; ++j) {
            if (valid & (1u << j)) {
                int i = tid + j * kTPB;
                unsigned long long key =
                    (((unsigned long long)order_key(my_sc[j])) << 32) |
                    (unsigned long long)(0xFFFFFFFFu - (unsigned int)i);
                best = key > best ? key : best;
            }
        }
        // Wave reduce (64 lanes), then one LDS atomic per wave.
        #pragma unroll
        for (int off = 32; off > 0; off >>= 1) {
            unsigned long long o = shfl_down_u64(best, off);
            best = o > best ? o : best;
        }
        if (lane == 0 && best != 0ULL) atomicMax(&s_maxkey[m], best);
        __syncthreads();

        unsigned long long k = s_maxkey[m];
        if (k != 0ULL) {  // block-uniform branch
            int idx = (int)(0xFFFFFFFFu - (unsigned int)(k & 0xFFFFFFFFull));
            if (tid == 0) {
                s_selidx[m]   = idx;
                s_selscore[m] = sc[idx];
                s_count       = m + 1;
            }
            // Same-address broadcast loads (L1 hit) — no extra barrier needed.
            float sxv = gx[idx];
            float syv = gy[idx];
            #pragma unroll
            for (int j = 0; j < kPerThread; ++j) {
                if (valid & (1u << j)) {
                    float dx = my_gx[j] - sxv;
                    float dy = my_gy[j] - syv;
                    if (dx * dx + dy * dy < kThresh2) valid &= ~(1u << j);
                }
            }
        }
        // If k==0, no candidate survives this or any later round (constraints
        // only grow) -> remaining rounds are no-ops, handled by fallback fill.
    }
    __syncthreads();

    // Unfilled slots fall back to round-0 winner (== sorted index 0).
    if (tid == 0) {
        for (int m = s_count; m < kModes; ++m) {
            s_selidx[m]   = s_selidx[0];
            s_selscore[m] = s_selscore[0];
        }
    }
    __syncthreads();

    // Gather trajectories: out[b,m,p,c] = trajs[b, 2p+c, sel_idx[m]].
    // Flat within a mode, offset e in [0,60) maps 1:1 (p*2+c == 2p+c).
    const float* tb   = trajs + (size_t)b * (2 * kSteps) * kN;
    float*       outt = out   + (size_t)b * kModes * (2 * kSteps);
    for (int e = tid; e < kModes * 2 * kSteps; e += kTPB) {
        int m  = e / (2 * kSteps);
        int pc = e - m * (2 * kSteps);
        outt[e] = tb[(size_t)pc * kN + s_selidx[m]];
    }
    if (tid < kModes) {
        out[(size_t)kB * kModes * 2 * kSteps + (size_t)b * kModes + tid] = s_selscore[tid];
    }
}

extern "C" void kernel_launch(void* const* d_in, const int* in_sizes, int n_in,
                              void* d_out, int out_size, void* d_ws, size_t ws_size,
                              hipStream_t stream) {
    const float* scores = (const float*)d_in[0];  // goals_scores [128, 4096]
    const float* trajs  = (const float*)d_in[1];  // traj_preds  [128, 60, 4096]
    const float* goals  = (const float*)d_in[2];  // pred_goals  [128, 2, 4096]
    float* out = (float*)d_out;
    densetnt_nms_kernel<<<kB, kTPB, 0, stream>>>(scores, trajs, goals, out);
}

// Round 2
// 166.535 us; speedup vs baseline: 1.0081x; 1.0081x over previous
//
#include <hip/hip_runtime.h>
#include <stdint.h>

// DenseTNT postprocess: per batch row, greedy goal-NMS (2 m threshold, strict <)
// over score-descending order, select 6 modes, gather trajs + scores.
//
// argsort+scan greedy NMS == 6 rounds of masked argmax ("best surviving
// candidate") -> no sort needed. Tie-break matches stable argsort:
// equal score -> lower original index wins (encoded in the u64 key).
//
// R2: block=1024 (4 cand/thread, float4 loads, 16 waves/CU for latency
// hiding), winner-goal broadcast via LDS (owner thread writes) instead of
// a same-address global load.

namespace {
constexpr int kB      = 128;
constexpr int kN      = 4096;
constexpr int kSteps  = 30;
constexpr int kModes  = 6;
constexpr int kTPB    = 1024;
constexpr int kPer    = kN / kTPB;   // 4 candidates per thread
constexpr float kThresh2 = 4.0f;     // THRESHOLD^2
}

// Monotone map float -> uint32 (preserves total order for all finite floats).
__device__ __forceinline__ unsigned int order_key(float f) {
    unsigned int u = __float_as_uint(f);
    return (u & 0x80000000u) ? ~u : (u | 0x80000000u);
}

__device__ __forceinline__ unsigned long long shfl_down_u64(unsigned long long v, int off) {
    unsigned int lo = (unsigned int)(v & 0xFFFFFFFFull);
    unsigned int hi = (unsigned int)(v >> 32);
    lo = __shfl_down(lo, off, 64);
    hi = __shfl_down(hi, off, 64);
    return (((unsigned long long)hi) << 32) | (unsigned long long)lo;
}

__global__ __launch_bounds__(kTPB)
void densetnt_nms_kernel(const float* __restrict__ scores,   // [B, N]
                         const float* __restrict__ trajs,    // [B, 2*P, N]
                         const float* __restrict__ goals,    // [B, 2, N]
                         float* __restrict__ out) {          // [B*6*60] trajs, then [B*6] scores
    const int b    = blockIdx.x;
    const int tid  = threadIdx.x;
    const int lane = tid & 63;

    __shared__ unsigned long long s_maxkey[kModes];
    __shared__ int   s_selidx[kModes];
    __shared__ float s_selscore[kModes];
    __shared__ float s_gx, s_gy;
    __shared__ int   s_count;

    const float4* sc4 = (const float4*)(scores + (size_t)b * kN);
    const float4* gx4 = (const float4*)(goals  + (size_t)b * 2 * kN);
    const float4* gy4 = (const float4*)(goals  + (size_t)b * 2 * kN + kN);

    // Each thread owns candidates [4*tid, 4*tid+3]; one float4 per array.
    float4 vsc = sc4[tid];
    float4 vgx = gx4[tid];
    float4 vgy = gy4[tid];
    float my_sc[kPer] = {vsc.x, vsc.y, vsc.z, vsc.w};
    float my_gx[kPer] = {vgx.x, vgx.y, vgx.z, vgx.w};
    float my_gy[kPer] = {vgy.x, vgy.y, vgy.z, vgy.w};

    if (tid < kModes) s_maxkey[tid] = 0ULL;   // 0 == "no valid candidate"
    if (tid == 0) s_count = 0;
    __syncthreads();

    unsigned int valid = 0xFu;  // 4-bit survival mask

    for (int m = 0; m < kModes; ++m) {
        // Local masked argmax: key = order(score)<<32 | ~idx  (max => highest
        // score, ties => lowest original index, matching stable argsort).
        unsigned long long best = 0ULL;
        #pragma unroll
        for (int c = 0; c < kPer; ++c) {
            if (valid & (1u << c)) {
                unsigned int i = (unsigned int)(tid * kPer + c);
                unsigned long long key =
                    (((unsigned long long)order_key(my_sc[c])) << 32) |
                    (unsigned long long)(0xFFFFFFFFu - i);
                best = key > best ? key : best;
            }
        }
        #pragma unroll
        for (int off = 32; off > 0; off >>= 1) {
            unsigned long long o = shfl_down_u64(best, off);
            best = o > best ? o : best;
        }
        if (lane == 0 && best != 0ULL) atomicMax(&s_maxkey[m], best);
        __syncthreads();

        const unsigned long long k = s_maxkey[m];  // block-uniform
        int idx = -1;
        if (k != 0ULL) {
            idx = (int)(0xFFFFFFFFu - (unsigned int)(k & 0xFFFFFFFFull));
            // Owner thread broadcasts the winner's goal through LDS.
            if (tid == (idx >> 2)) {
                const int c = idx & 3;
                s_gx = my_gx[c];
                s_gy = my_gy[c];
                s_selidx[m]   = idx;
                s_selscore[m] = my_sc[c];
                s_count       = m + 1;
            }
        }
        __syncthreads();

        if (k != 0ULL) {
            const float sxv = s_gx, syv = s_gy;
            #pragma unroll
            for (int c = 0; c < kPer; ++c) {
                if (valid & (1u << c)) {
                    float dx = my_gx[c] - sxv;
                    float dy = my_gy[c] - syv;
                    if (dx * dx + dy * dy < kThresh2) valid &= ~(1u << c);
                }
            }
        }
        // k==0: constraints only grow -> later rounds also empty; fallback fills.
    }

    // Unfilled slots fall back to round-0 winner (== sorted index 0).
    if (tid == 0) {
        for (int m = s_count; m < kModes; ++m) {
            s_selidx[m]   = s_selidx[0];
            s_selscore[m] = s_selscore[0];
        }
    }
    __syncthreads();

    // Gather trajectories: out[b,m,p,c] = trajs[b, 2p+c, sel_idx[m]].
    const float* tb   = trajs + (size_t)b * (2 * kSteps) * kN;
    float*       outt = out   + (size_t)b * kModes * (2 * kSteps);
    if (tid < kModes * 2 * kSteps) {
        int m  = tid / (2 * kSteps);
        int pc = tid - m * (2 * kSteps);
        outt[tid] = tb[(size_t)pc * kN + s_selidx[m]];
    }
    if (tid < kModes) {
        out[(size_t)kB * kModes * 2 * kSteps + (size_t)b * kModes + tid] = s_selscore[tid];
    }
}

extern "C" void kernel_launch(void* const* d_in, const int* in_sizes, int n_in,
                              void* d_out, int out_size, void* d_ws, size_t ws_size,
                              hipStream_t stream) {
    const float* scores = (const float*)d_in[0];  // goals_scores [128, 4096]
    const float* trajs  = (const float*)d_in[1];  // traj_preds  [128, 60, 4096]
    const float* goals  = (const float*)d_in[2];  // pred_goals  [128, 2, 4096]
    float* out = (float*)d_out;
    densetnt_nms_kernel<<<kB, kTPB, 0, stream>>>(scores, trajs, goals, out);
}